// Round 3
// baseline (259.988 us; speedup 1.0000x reference)
//
#include <hip/hip_runtime.h>
#include <hip/hip_bf16.h>

#define DIMV 64

static constexpr float F_EPS  = 1e-7f;
static constexpr float F_MINN = 1e-15f;
static constexpr float F_MAXN = 1.0f - 4e-3f;   // proj maxnorm

__device__ __forceinline__ float frcp(float x) { return __builtin_amdgcn_rcpf(x); }
__device__ __forceinline__ float frsq(float x) { return __builtin_amdgcn_rsqf(x); }
// tanh(x) for x>=0: 1 - 2/(e^{2x}+1), via fast exp
__device__ __forceinline__ float tanh_fast(float x) {
    float e = __expf(2.0f * x);
    return 1.0f - 2.0f * frcp(e + 1.0f);
}

__device__ __forceinline__ float wave_sum1(float v) {
#pragma unroll
    for (int off = 32; off > 0; off >>= 1)
        v += __shfl_xor(v, off, 64);
    return v;
}
__device__ __forceinline__ void wave_sum2(float& a, float& b) {
#pragma unroll
    for (int off = 32; off > 0; off >>= 1) {
        a += __shfl_xor(a, off, 64);
        b += __shfl_xor(b, off, 64);
    }
}
__device__ __forceinline__ void wave_sum3(float& a, float& b, float& c) {
#pragma unroll
    for (int off = 32; off > 0; off >>= 1) {
        a += __shfl_xor(a, off, 64);
        b += __shfl_xor(b, off, 64);
        c += __shfl_xor(c, off, 64);
    }
}

// q = proj(expmap0(ent[it])); returns per-lane q and ||q||^2
__device__ __forceinline__ void item_q(const float* __restrict__ ent, int it,
                                       int lane, float& q, float& y2) {
    const float iv = ent[(long)it * DIMV + lane];
    float n2 = wave_sum1(iv * iv);
    float n  = fmaxf(sqrtf(n2), F_MINN);
    float te = tanh_fast(n);
    float s  = (te > F_MAXN) ? F_MAXN * frcp(te) : 1.0f;
    q  = iv * (te * frcp(n)) * s;
    float qn = te * s;
    y2 = qn * qn;
}

// ---------------- kernel 1: per-(b,halfM) partials ----------------
// grid = 2*B blocks, 256 threads (4 waves). block -> (b = bid>>1, half = bid&1)
// wave w: h = w>>1, m-range = half*(M/2) + (w&1)*(M/4) .. +M/4
// ws slot (b, half, h): 66 floats  [0..63]=accA  [64]=accS
template<int MC>
__global__ __launch_bounds__(256, 8) void hpnet_k1(
        const int*   __restrict__ items,
        const int*   __restrict__ mem_h,
        const int*   __restrict__ mem_r,
        const int*   __restrict__ mem_t,
        const float* __restrict__ ent,
        const float* __restrict__ rel,
        float*       __restrict__ ws,
        int B, int M)
{
    const int bid  = blockIdx.x;
    const int b    = bid >> 1;
    const int half = bid & 1;
    const int tid  = threadIdx.x;
    const int wave = tid >> 6;
    const int lane = tid & 63;
    const int h    = wave >> 1;
    const int mc   = MC ? MC : (M >> 2);
    const int mst  = half * (M >> 1) + (wave & 1) * mc;

    float q, y2;
    item_q(ent, items[b], lane, q, y2);

    float accA = 0.0f, accS = 0.0f;
    const long ibase = ((long)h * B + b) * M + mst;

#pragma unroll 2
    for (int k = 0; k < mc; ++k) {
        const int ih  = __builtin_amdgcn_readfirstlane(mem_h[ibase + k]);
        const int ir  = __builtin_amdgcn_readfirstlane(mem_r[ibase + k]);
        const int itt = __builtin_amdgcn_readfirstlane(mem_t[ibase + k]);

        const float*  hp = ent + (long)ih * DIMV;
        const float4* Rr = (const float4*)(rel + (long)ir * (DIMV * DIMV))
                           + lane * (DIMV / 4);
        // 4 independent accumulator chains
        float u[4] = {0.f, 0.f, 0.f, 0.f};
#pragma unroll
        for (int j = 0; j < 16; ++j) {
            float4 rv = Rr[j];
            u[j & 3] = fmaf(rv.x, hp[4 * j + 0], u[j & 3]);
            u[j & 3] = fmaf(rv.y, hp[4 * j + 1], u[j & 3]);
            u[j & 3] = fmaf(rv.z, hp[4 * j + 2], u[j & 3]);
            u[j & 3] = fmaf(rv.w, hp[4 * j + 3], u[j & 3]);
        }
        const float uloc = ((u[0] + u[1]) + (u[2] + u[3])) * 0.1f;
        const float tv   = ent[(long)itt * DIMV + lane];

        // one merged 3-way butterfly: ||u||^2, u.q, ||t||^2
        float uu = uloc * uloc, uq = uloc * q, tt = tv * tv;
        wave_sum3(uu, uq, tt);

        // Rh = proj(expmap0(u)): only norm + dot needed (p never materialized)
        float nu = fmaxf(sqrtf(uu), F_MINN);
        float te = tanh_fast(nu);
        float sc = (te > F_MAXN) ? F_MAXN * frcp(te) : 1.0f;
        float pn = te * sc;
        float x2 = pn * pn;
        float xy = -(pn * frcp(nu)) * uq;          // (-Rh).q

        float A_  = 1.0f + 2.0f * xy + y2;
        float B_  = 1.0f - x2;
        float nm2 = fmaxf(A_ * A_ * x2 + B_ * B_ * y2 + 2.0f * A_ * B_ * xy, 0.0f);
        float den = fmaxf(1.0f + 2.0f * xy + x2 * y2, 1e-15f);
        float v   = fminf(sqrtf(nm2) * frcp(den), 1.0f - F_EPS);
        float dd  = __logf((1.0f + v) * frcp(1.0f - v));   // 2*artanh(v)
        float att = __expf(fmaf(-0.2f, dd * dd, -0.05f));

        // t path
        float nt  = fmaxf(sqrtf(tt), F_MINN);
        float tte = tanh_fast(nt);
        float ts  = (tte > F_MAXN) ? F_MAXN * frcp(tte) : 1.0f;
        float ptn = tte * ts;
        float a2  = ptn * ptn;
        float i1a = frcp(1.0f + a2);
        float kn2 = 4.0f * a2 * i1a * i1a;
        float lf  = frsq(fmaxf(1.0f - kn2, F_EPS));
        float p1  = lf * att;
        float kfc = 2.0f * ptn * frcp(nt) * i1a;   // kle_t = kfc * tv

        accS += p1;
        accA = fmaf(p1 * kfc, tv, accA);
    }

    __shared__ float A_l[4][DIMV];
    __shared__ float S_l[4];
    A_l[wave][lane] = accA;
    if (lane == 0) S_l[wave] = accS;
    __syncthreads();

    if (wave < 2) {   // wave 0 -> h=0, wave 1 -> h=1
        float a = A_l[2 * wave][lane] + A_l[2 * wave + 1][lane];
        float s = S_l[2 * wave] + S_l[2 * wave + 1];
        long slot = ((long)(b * 2 + half) * 2 + wave) * 66;
        ws[slot + lane] = a;
        if (lane == 0) ws[slot + 64] = s;
    }
}

// ---------------- kernel 2: per-b epilogue ----------------
// grid = ceil(B/4) blocks, 256 threads; wave handles b = bid*4 + wave
__global__ __launch_bounds__(256, 8) void hpnet_k2(
        const int*   __restrict__ items,
        const float* __restrict__ ent,
        const float* __restrict__ ws,
        float*       __restrict__ out,
        int B)
{
    const int wave = threadIdx.x >> 6;
    const int lane = threadIdx.x & 63;
    const int b    = blockIdx.x * 4 + wave;
    if (b >= B) return;

    float q, y2;
    item_q(ent, items[b], lane, q, y2);

    auto slot = [](int bb, int half, int hh) -> long {
        return ((long)(bb * 2 + half) * 2 + hh) * 66;
    };
    float A0 = ws[slot(b, 0, 0) + lane] + ws[slot(b, 1, 0) + lane];
    float A1 = ws[slot(b, 0, 1) + lane] + ws[slot(b, 1, 1) + lane];
    float S0 = ws[slot(b, 0, 0) + 64] + ws[slot(b, 1, 0) + 64];
    float S1 = ws[slot(b, 0, 1) + 64] + ws[slot(b, 1, 1) + 64];

    float k0 = A0 * frcp(fmaxf(S0, F_EPS));
    float k1 = A1 * frcp(fmaxf(S1, F_EPS));

    float n0 = k0 * k0, n1 = k1 * k1;
    wave_sum2(n0, n1);
    float p20 = frsq(fmaxf(1.0f - n0, F_EPS));
    float p21 = frsq(fmaxf(1.0f - n1, F_EPS));
    float o   = (p20 * k0 + p21 * k1) * frcp(fmaxf(p20 + p21, F_EPS));

    float oo = o * o, oq = o * q;
    wave_sum2(oo, oq);
    float kd    = 1.0f + sqrtf(fmaxf(1.0f - oo, F_EPS));
    float invkd = frcp(kd);
    float ko2   = oo * invkd * invkd;              // ||klein_to(o)||^2
    float nk    = fmaxf(sqrtf(ko2), F_MINN);
    float ps    = (nk > F_MAXN) ? F_MAXN * frcp(nk) : 1.0f;
    float x2    = (nk * ps) * (nk * ps);
    float xy    = -(ps * invkd) * oq;              // (-hyp_o).q

    float A_  = 1.0f + 2.0f * xy + y2;
    float B_  = 1.0f - x2;
    float nm2 = fmaxf(A_ * A_ * x2 + B_ * B_ * y2 + 2.0f * A_ * B_ * xy, 0.0f);
    float den = fmaxf(1.0f + 2.0f * xy + x2 * y2, 1e-15f);
    float v   = fminf(sqrtf(nm2) * frcp(den), 1.0f - F_EPS);
    float dd  = __logf((1.0f + v) * frcp(1.0f - v));
    float d2  = dd * dd;

    float scr = frcp(__expf(fminf(d2 - 2.0f, 40.0f)) + 1.0f);
    if (lane == 0) out[b] = scr;
}

extern "C" void kernel_launch(void* const* d_in, const int* in_sizes, int n_in,
                              void* d_out, int out_size, void* d_ws, size_t ws_size,
                              hipStream_t stream) {
    // 0 users 1 items 2 labels 3 mem_h 4 mem_r 5 mem_t 6 entity_emb 7 rela_plus 8 relation_emb
    const int*   items = (const int*)d_in[1];
    const int*   mh    = (const int*)d_in[3];
    const int*   mr    = (const int*)d_in[4];
    const int*   mt    = (const int*)d_in[5];
    const float* ent   = (const float*)d_in[6];
    const float* rel   = (const float*)d_in[8];
    float* out = (float*)d_out;
    float* wsf = (float*)d_ws;

    const int B = in_sizes[1];              // 1024
    const int M = in_sizes[3] / (2 * B);    // 32 (H=2)

    if (M == 32) {
        hpnet_k1<8><<<dim3(2 * B), dim3(256), 0, stream>>>(items, mh, mr, mt,
                                                           ent, rel, wsf, B, M);
    } else {
        hpnet_k1<0><<<dim3(2 * B), dim3(256), 0, stream>>>(items, mh, mr, mt,
                                                           ent, rel, wsf, B, M);
    }
    hpnet_k2<<<dim3((B + 3) / 4), dim3(256), 0, stream>>>(items, ent, wsf, out, B);
}

// Round 4
// 165.259 us; speedup vs baseline: 1.5732x; 1.5732x over previous
//
#include <hip/hip_runtime.h>
#include <hip/hip_bf16.h>

#define DIMV 64

static constexpr float F_EPS  = 1e-7f;
static constexpr float F_MINN = 1e-15f;
static constexpr float F_MAXN = 1.0f - 4e-3f;   // proj maxnorm

__device__ __forceinline__ float frcp(float x) { return __builtin_amdgcn_rcpf(x); }
__device__ __forceinline__ float frsq(float x) { return __builtin_amdgcn_rsqf(x); }
__device__ __forceinline__ float tanh_fast(float x) {           // x >= 0
    float e = __expf(2.0f * x);
    return 1.0f - 2.0f * frcp(e + 1.0f);
}

__device__ __forceinline__ float wave_sum1(float v) {
#pragma unroll
    for (int off = 32; off > 0; off >>= 1) v += __shfl_xor(v, off, 64);
    return v;
}
__device__ __forceinline__ void wave_sum2(float& a, float& b) {
#pragma unroll
    for (int off = 32; off > 0; off >>= 1) {
        a += __shfl_xor(a, off, 64);
        b += __shfl_xor(b, off, 64);
    }
}

// ---------------- counting sort of tasks by relation (32 bins) ----------------
__global__ void k_hist(const int* __restrict__ mr, int n, int* __restrict__ hist) {
    __shared__ int lh[32];
    if (threadIdx.x < 32) lh[threadIdx.x] = 0;
    __syncthreads();
    for (int i = blockIdx.x * blockDim.x + threadIdx.x; i < n; i += gridDim.x * blockDim.x)
        atomicAdd(&lh[mr[i]], 1);
    __syncthreads();
    if (threadIdx.x < 32 && lh[threadIdx.x]) atomicAdd(&hist[threadIdx.x], lh[threadIdx.x]);
}

__global__ void k_scan(const int* __restrict__ hist, int* __restrict__ cursor) {
    if (threadIdx.x == 0) {
        int acc = 0;
        for (int r = 0; r < 32; ++r) { cursor[r] = acc; acc += hist[r]; }
    }
}

__global__ void k_scatter(const int* __restrict__ mr, int n,
                          int* __restrict__ cursor, int* __restrict__ bins) {
    __shared__ int lcnt[32], lbase[32];
    const int tid = threadIdx.x;
    if (tid < 32) lcnt[tid] = 0;
    __syncthreads();
    int idxA[4], rnkA[4], relA[4];
    int cnt = 0;
    int i = blockIdx.x * blockDim.x + tid;
#pragma unroll
    for (int kk = 0; kk < 4; ++kk) {
        if (i < n) {
            int r = mr[i];
            idxA[kk] = i; relA[kk] = r;
            rnkA[kk] = atomicAdd(&lcnt[r], 1);
            cnt = kk + 1;
        }
        i += gridDim.x * blockDim.x;
    }
    __syncthreads();
    if (tid < 32) lbase[tid] = atomicAdd(&cursor[tid], lcnt[tid]);
    __syncthreads();
#pragma unroll
    for (int kk = 0; kk < 4; ++kk)
        if (kk < cnt) bins[lbase[relA[kk]] + rnkA[kk]] = idxA[kk];
}

// ---------------- q precompute: q = proj(expmap0(ent[item])) ----------------
__global__ __launch_bounds__(256) void k_q(const int* __restrict__ items,
                                           const float* __restrict__ ent,
                                           float* __restrict__ qbuf,
                                           float* __restrict__ y2buf, int B) {
    const int wave = threadIdx.x >> 6, lane = threadIdx.x & 63;
    const int b = blockIdx.x * 4 + wave;
    if (b >= B) return;
    const int it = items[b];
    const float iv = ent[(long)it * DIMV + lane];
    float n2 = wave_sum1(iv * iv);
    float n  = fmaxf(sqrtf(n2), F_MINN);
    float te = tanh_fast(n);
    float s  = (te > F_MAXN) ? F_MAXN * frcp(te) : 1.0f;
    qbuf[(long)b * DIMV + lane] = iv * (te * frcp(n)) * s;
    if (lane == 0) { float qn = te * s; y2buf[b] = qn * qn; }
}

// ---------------- pass 1: attention scalars, relation-binned ----------------
// One wave processes PW consecutive sorted tasks; R row `lane` lives in 64 VGPRs.
// MM==0 -> runtime div/mod path.
template<int MM, int BB>
__global__ __launch_bounds__(256, 4) void k_att(
        const int*   __restrict__ mem_h,
        const int*   __restrict__ mem_r,
        const float* __restrict__ ent,
        const float* __restrict__ rel,
        const int*   __restrict__ bins,
        const float* __restrict__ qbuf,
        const float* __restrict__ y2buf,
        float*       __restrict__ attbuf,
        int M, int B, int ntask, int per_wave)
{
    const int lane = threadIdx.x & 63;
    const int wid  = blockIdx.x * 4 + (threadIdx.x >> 6);
    const int start = wid * per_wave;

    float Rreg[DIMV];
    int cur_r = -1;

    for (int k = 0; k < per_wave; ++k) {
        const int idx = start + k;
        if (idx >= ntask) return;
        const int t = __builtin_amdgcn_readfirstlane(bins[idx]);
        const int r = __builtin_amdgcn_readfirstlane(mem_r[t]);
        if (r != cur_r) {
            const float4* Rp = (const float4*)(rel + (long)r * (DIMV * DIMV)) + lane * 16;
#pragma unroll
            for (int j = 0; j < 16; ++j) {
                float4 v = Rp[j];
                Rreg[4 * j + 0] = v.x; Rreg[4 * j + 1] = v.y;
                Rreg[4 * j + 2] = v.z; Rreg[4 * j + 3] = v.w;
            }
            cur_r = r;
        }
        const int ih = __builtin_amdgcn_readfirstlane(mem_h[t]);
        const int b  = MM ? ((t >> 5) & (BB - 1))
                          : (int)(((unsigned)t / (unsigned)M) % (unsigned)B);

        const float* hp = ent + (long)ih * DIMV;          // wave-uniform -> s_loads
        const float  q  = qbuf[(long)b * DIMV + lane];
        const float  y2 = y2buf[b];

        float u0 = 0.f, u1 = 0.f, u2 = 0.f, u3 = 0.f;
#pragma unroll
        for (int j = 0; j < 16; ++j) {
            u0 = fmaf(Rreg[4 * j + 0], hp[4 * j + 0], u0);
            u1 = fmaf(Rreg[4 * j + 1], hp[4 * j + 1], u1);
            u2 = fmaf(Rreg[4 * j + 2], hp[4 * j + 2], u2);
            u3 = fmaf(Rreg[4 * j + 3], hp[4 * j + 3], u3);
        }
        const float u = ((u0 + u1) + (u2 + u3)) * 0.1f;

        float uu = u * u, uq = u * q;
        wave_sum2(uu, uq);

        float nu = fmaxf(sqrtf(uu), F_MINN);
        float te = tanh_fast(nu);
        float sc = (te > F_MAXN) ? F_MAXN * frcp(te) : 1.0f;
        float pn = te * sc;
        float x2 = pn * pn;
        float xy = -(pn * frcp(nu)) * uq;                  // (-Rh).q

        float A_  = 1.0f + 2.0f * xy + y2;
        float B_  = 1.0f - x2;
        float nm2 = fmaxf(A_ * A_ * x2 + B_ * B_ * y2 + 2.0f * A_ * B_ * xy, 0.0f);
        float den = fmaxf(1.0f + 2.0f * xy + x2 * y2, 1e-15f);
        float v   = fminf(sqrtf(nm2) * frcp(den), 1.0f - F_EPS);
        float dd  = __logf((1.0f + v) * frcp(1.0f - v));   // 2*artanh(v)
        float att = __expf(fmaf(-0.2f, dd * dd, -0.05f));

        if (lane == 0) attbuf[t] = att;
    }
}

// ---------------- pass 2: t-path aggregation + epilogue, block per b ----------------
__global__ __launch_bounds__(256) void k_agg(
        const int*   __restrict__ mem_t,
        const float* __restrict__ ent,
        const float* __restrict__ attbuf,
        const float* __restrict__ qbuf,
        const float* __restrict__ y2buf,
        float*       __restrict__ out,
        int B, int M)
{
    const int b    = blockIdx.x;
    const int wave = threadIdx.x >> 6;
    const int lane = threadIdx.x & 63;
    const int h    = wave >> 1;
    const int mhalf = M >> 1;
    const int mst  = (wave & 1) * mhalf;

    const float q  = qbuf[(long)b * DIMV + lane];
    const float y2 = y2buf[b];

    float accA = 0.0f, accS = 0.0f;
    const long ibase = ((long)h * B + b) * M + mst;

    for (int k = 0; k < mhalf; ++k) {
        const long t  = ibase + k;
        const int itt = __builtin_amdgcn_readfirstlane(mem_t[t]);
        const float av = attbuf[t];                         // uniform -> s_load
        const float tv = ent[(long)itt * DIMV + lane];
        float tt = wave_sum1(tv * tv);

        float nt  = fmaxf(sqrtf(tt), F_MINN);
        float tte = tanh_fast(nt);
        float ts  = (tte > F_MAXN) ? F_MAXN * frcp(tte) : 1.0f;
        float ptn = tte * ts;
        float a2  = ptn * ptn;
        float i1a = frcp(1.0f + a2);
        float kn2 = 4.0f * a2 * i1a * i1a;
        float lf  = frsq(fmaxf(1.0f - kn2, F_EPS));
        float p1  = lf * av;
        float kfc = 2.0f * ptn * frcp(nt) * i1a;            // kle_t = kfc * tv

        accS += p1;
        accA = fmaf(p1 * kfc, tv, accA);
    }

    __shared__ float A_l[4][DIMV];
    __shared__ float S_l[4];
    A_l[wave][lane] = accA;
    if (lane == 0) S_l[wave] = accS;
    __syncthreads();

    if (wave == 0) {
        float k0 = (A_l[0][lane] + A_l[1][lane]) * frcp(fmaxf(S_l[0] + S_l[1], F_EPS));
        float k1 = (A_l[2][lane] + A_l[3][lane]) * frcp(fmaxf(S_l[2] + S_l[3], F_EPS));
        float n0 = k0 * k0, n1 = k1 * k1;
        wave_sum2(n0, n1);
        float p20 = frsq(fmaxf(1.0f - n0, F_EPS));
        float p21 = frsq(fmaxf(1.0f - n1, F_EPS));
        float o   = (p20 * k0 + p21 * k1) * frcp(fmaxf(p20 + p21, F_EPS));

        float oo = o * o, oq = o * q;
        wave_sum2(oo, oq);
        float kd    = 1.0f + sqrtf(fmaxf(1.0f - oo, F_EPS));
        float invkd = frcp(kd);
        float ko2   = oo * invkd * invkd;
        float nk    = fmaxf(sqrtf(ko2), F_MINN);
        float ps    = (nk > F_MAXN) ? F_MAXN * frcp(nk) : 1.0f;
        float x2    = (nk * ps) * (nk * ps);
        float xy    = -(ps * invkd) * oq;

        float A_  = 1.0f + 2.0f * xy + y2;
        float B_  = 1.0f - x2;
        float nm2 = fmaxf(A_ * A_ * x2 + B_ * B_ * y2 + 2.0f * A_ * B_ * xy, 0.0f);
        float den = fmaxf(1.0f + 2.0f * xy + x2 * y2, 1e-15f);
        float v   = fminf(sqrtf(nm2) * frcp(den), 1.0f - F_EPS);
        float dd  = __logf((1.0f + v) * frcp(1.0f - v));
        float d2  = dd * dd;

        float scr = frcp(__expf(fminf(d2 - 2.0f, 40.0f)) + 1.0f);
        if (lane == 0) out[b] = scr;
    }
}

extern "C" void kernel_launch(void* const* d_in, const int* in_sizes, int n_in,
                              void* d_out, int out_size, void* d_ws, size_t ws_size,
                              hipStream_t stream) {
    // 0 users 1 items 2 labels 3 mem_h 4 mem_r 5 mem_t 6 entity 7 rela_plus 8 relation
    const int*   items = (const int*)d_in[1];
    const int*   mh    = (const int*)d_in[3];
    const int*   mr    = (const int*)d_in[4];
    const int*   mt    = (const int*)d_in[5];
    const float* ent   = (const float*)d_in[6];
    const float* rel   = (const float*)d_in[8];
    float* out = (float*)d_out;

    const int B = in_sizes[1];              // 1024
    const int n = in_sizes[3];              // H*B*M = 65536
    const int M = n / (2 * B);              // 32 (H=2)

    // ws layout (floats): qbuf[B*64] | y2[B] | att[n] | hist[32] offs-free cursor[32] bins[n] (ints)
    float* qbuf   = (float*)d_ws;
    float* y2buf  = qbuf + (size_t)B * DIMV;
    float* attbuf = y2buf + B;
    int*   hist   = (int*)(attbuf + n);
    int*   cursor = hist + 32;
    int*   bins   = cursor + 32;

    hipMemsetAsync(hist, 0, 32 * sizeof(int), stream);
    k_hist<<<dim3(64), dim3(256), 0, stream>>>(mr, n, hist);
    k_scan<<<dim3(1), dim3(64), 0, stream>>>(hist, cursor);
    {
        int g = (n + 1023) / 1024;          // 4 items per thread @256 thr
        k_scatter<<<dim3(g), dim3(256), 0, stream>>>(mr, n, cursor, bins);
    }
    k_q<<<dim3((B + 3) / 4), dim3(256), 0, stream>>>(items, ent, qbuf, y2buf, B);

    const int per_wave = 16;
    const int g_att = (n + per_wave * 4 - 1) / (per_wave * 4);
    if (M == 32 && B == 1024)
        k_att<32, 1024><<<dim3(g_att), dim3(256), 0, stream>>>(
            mh, mr, ent, rel, bins, qbuf, y2buf, attbuf, M, B, n, per_wave);
    else
        k_att<0, 0><<<dim3(g_att), dim3(256), 0, stream>>>(
            mh, mr, ent, rel, bins, qbuf, y2buf, attbuf, M, B, n, per_wave);

    k_agg<<<dim3(B), dim3(256), 0, stream>>>(mt, ent, attbuf, qbuf, y2buf, out, B, M);
}

// Round 5
// 162.575 us; speedup vs baseline: 1.5992x; 1.0165x over previous
//
#include <hip/hip_runtime.h>
#include <hip/hip_bf16.h>

#define DIMV 64

static constexpr float F_EPS  = 1e-7f;
static constexpr float F_MINN = 1e-15f;
static constexpr float F_MAXN = 1.0f - 4e-3f;   // proj maxnorm

__device__ __forceinline__ float frcp(float x) { return __builtin_amdgcn_rcpf(x); }
__device__ __forceinline__ float frsq(float x) { return __builtin_amdgcn_rsqf(x); }
__device__ __forceinline__ float tanh_fast(float x) {           // x >= 0
    float e = __expf(2.0f * x);
    return 1.0f - 2.0f * frcp(e + 1.0f);
}

__device__ __forceinline__ float wave_sum1(float v) {
#pragma unroll
    for (int off = 32; off > 0; off >>= 1) v += __shfl_xor(v, off, 64);
    return v;
}
__device__ __forceinline__ void wave_sum2(float& a, float& b) {
#pragma unroll
    for (int off = 32; off > 0; off >>= 1) {
        a += __shfl_xor(a, off, 64);
        b += __shfl_xor(b, off, 64);
    }
}
__device__ __forceinline__ void wave_sum3(float& a, float& b, float& c) {
#pragma unroll
    for (int off = 32; off > 0; off >>= 1) {
        a += __shfl_xor(a, off, 64);
        b += __shfl_xor(b, off, 64);
        c += __shfl_xor(c, off, 64);
    }
}

// ---------------- counting sort of tasks by relation (32 bins) ----------------
__global__ void k_hist(const int* __restrict__ mr, int n, int* __restrict__ hist) {
    __shared__ int lh[32];
    if (threadIdx.x < 32) lh[threadIdx.x] = 0;
    __syncthreads();
    for (int i = blockIdx.x * blockDim.x + threadIdx.x; i < n; i += gridDim.x * blockDim.x)
        atomicAdd(&lh[mr[i]], 1);
    __syncthreads();
    if (threadIdx.x < 32 && lh[threadIdx.x]) atomicAdd(&hist[threadIdx.x], lh[threadIdx.x]);
}

__global__ void k_scan(const int* __restrict__ hist, int* __restrict__ cursor) {
    if (threadIdx.x == 0) {
        int acc = 0;
        for (int r = 0; r < 32; ++r) { cursor[r] = acc; acc += hist[r]; }
    }
}

__global__ void k_scatter(const int* __restrict__ mr, int n,
                          int* __restrict__ cursor, int* __restrict__ bins) {
    __shared__ int lcnt[32], lbase[32];
    const int tid = threadIdx.x;
    if (tid < 32) lcnt[tid] = 0;
    __syncthreads();
    int idxA[4], rnkA[4], relA[4];
    int cnt = 0;
    int i = blockIdx.x * blockDim.x + tid;
#pragma unroll
    for (int kk = 0; kk < 4; ++kk) {
        if (i < n) {
            int r = mr[i];
            idxA[kk] = i; relA[kk] = r;
            rnkA[kk] = atomicAdd(&lcnt[r], 1);
            cnt = kk + 1;
        }
        i += gridDim.x * blockDim.x;
    }
    __syncthreads();
    if (tid < 32) lbase[tid] = atomicAdd(&cursor[tid], lcnt[tid]);
    __syncthreads();
#pragma unroll
    for (int kk = 0; kk < 4; ++kk)
        if (kk < cnt) bins[lbase[relA[kk]] + rnkA[kk]] = idxA[kk];
}

// ---------------- q precompute: q = proj(expmap0(ent[item])) ----------------
__global__ __launch_bounds__(256) void k_q(const int* __restrict__ items,
                                           const float* __restrict__ ent,
                                           float* __restrict__ qbuf,
                                           float* __restrict__ y2buf, int B) {
    const int wave = threadIdx.x >> 6, lane = threadIdx.x & 63;
    const int b = blockIdx.x * 4 + wave;
    if (b >= B) return;
    const int it = items[b];
    const float iv = ent[(long)it * DIMV + lane];
    float n2 = wave_sum1(iv * iv);
    float n  = fmaxf(sqrtf(n2), F_MINN);
    float te = tanh_fast(n);
    float s  = (te > F_MAXN) ? F_MAXN * frcp(te) : 1.0f;
    qbuf[(long)b * DIMV + lane] = iv * (te * frcp(n)) * s;
    if (lane == 0) { float qn = te * s; y2buf[b] = qn * qn; }
}

// ---------------- main pass: att + t-path scalars, relation-binned ----------------
// One wave processes per_wave consecutive relation-sorted tasks.
// R row `lane` lives in 16 NAMED float4s (64 VGPRs) -> no alloca, no scratch.
template<int MM, int BB>
__global__ __launch_bounds__(256, 4) void k_main(
        const int*   __restrict__ mem_h,
        const int*   __restrict__ mem_r,
        const int*   __restrict__ mem_t,
        const float* __restrict__ ent,
        const float* __restrict__ rel,
        const int*   __restrict__ bins,
        const float* __restrict__ qbuf,
        const float* __restrict__ y2buf,
        float2*      __restrict__ pkbuf,
        int M, int B, int ntask, int per_wave)
{
    const int lane = threadIdx.x & 63;
    const int wid  = blockIdx.x * 4 + (threadIdx.x >> 6);
    const int start = wid * per_wave;

    float4 r0, r1, r2, r3, r4, r5, r6, r7, r8, r9, r10, r11, r12, r13, r14, r15;
    int cur_r = -1;

    for (int k = 0; k < per_wave; ++k) {
        const int idx = start + k;
        if (idx >= ntask) return;
        const int t = __builtin_amdgcn_readfirstlane(bins[idx]);
        const int r = __builtin_amdgcn_readfirstlane(mem_r[t]);
        if (r != cur_r) {
            const float4* Rp = (const float4*)(rel + (long)r * (DIMV * DIMV)) + lane * 16;
            r0  = Rp[0];  r1  = Rp[1];  r2  = Rp[2];  r3  = Rp[3];
            r4  = Rp[4];  r5  = Rp[5];  r6  = Rp[6];  r7  = Rp[7];
            r8  = Rp[8];  r9  = Rp[9];  r10 = Rp[10]; r11 = Rp[11];
            r12 = Rp[12]; r13 = Rp[13]; r14 = Rp[14]; r15 = Rp[15];
            cur_r = r;
        }
        const int ih  = __builtin_amdgcn_readfirstlane(mem_h[t]);
        const int itt = __builtin_amdgcn_readfirstlane(mem_t[t]);
        const int b   = MM ? ((t / MM) & (BB - 1))
                           : (int)(((unsigned)t / (unsigned)M) % (unsigned)B);

        const float* hp = ent + (long)ih * DIMV;           // wave-uniform -> s_loads
        const float  tv = ent[(long)itt * DIMV + lane];    // coalesced 256B row
        const float  q  = qbuf[(long)b * DIMV + lane];
        const float  y2 = y2buf[b];

        float u0 = 0.f, u1 = 0.f, u2 = 0.f, u3 = 0.f;
#define STEP(J, RV) \
        u0 = fmaf(RV.x, hp[4 * (J) + 0], u0); \
        u1 = fmaf(RV.y, hp[4 * (J) + 1], u1); \
        u2 = fmaf(RV.z, hp[4 * (J) + 2], u2); \
        u3 = fmaf(RV.w, hp[4 * (J) + 3], u3);
        STEP(0, r0)  STEP(1, r1)  STEP(2, r2)  STEP(3, r3)
        STEP(4, r4)  STEP(5, r5)  STEP(6, r6)  STEP(7, r7)
        STEP(8, r8)  STEP(9, r9)  STEP(10, r10) STEP(11, r11)
        STEP(12, r12) STEP(13, r13) STEP(14, r14) STEP(15, r15)
#undef STEP
        const float u = ((u0 + u1) + (u2 + u3)) * 0.1f;

        // merged butterfly: ||u||^2, u.q, ||t||^2
        float uu = u * u, uq = u * q, tt = tv * tv;
        wave_sum3(uu, uq, tt);

        // attention scalar
        float nu = fmaxf(sqrtf(uu), F_MINN);
        float te = tanh_fast(nu);
        float sc = (te > F_MAXN) ? F_MAXN * frcp(te) : 1.0f;
        float pn = te * sc;
        float x2 = pn * pn;
        float xy = -(pn * frcp(nu)) * uq;                  // (-Rh).q

        float A_  = 1.0f + 2.0f * xy + y2;
        float B_  = 1.0f - x2;
        float nm2 = fmaxf(A_ * A_ * x2 + B_ * B_ * y2 + 2.0f * A_ * B_ * xy, 0.0f);
        float den = fmaxf(1.0f + 2.0f * xy + x2 * y2, 1e-15f);
        float v   = fminf(sqrtf(nm2) * frcp(den), 1.0f - F_EPS);
        float dd  = __logf((1.0f + v) * frcp(1.0f - v));   // 2*artanh(v)
        float att = __expf(fmaf(-0.2f, dd * dd, -0.05f));

        // t-path scalars
        float nt  = fmaxf(sqrtf(tt), F_MINN);
        float tte = tanh_fast(nt);
        float ts  = (tte > F_MAXN) ? F_MAXN * frcp(tte) : 1.0f;
        float ptn = tte * ts;
        float a2  = ptn * ptn;
        float i1a = frcp(1.0f + a2);
        float kn2 = 4.0f * a2 * i1a * i1a;
        float lf  = frsq(fmaxf(1.0f - kn2, F_EPS));
        float p1  = lf * att;
        float kfc = 2.0f * ptn * frcp(nt) * i1a;           // kle_t = kfc * tv

        if (lane == 0) pkbuf[t] = make_float2(p1, kfc);
    }
}

// ---------------- aggregation + epilogue: block per b ----------------
__global__ __launch_bounds__(256) void k_agg(
        const int*    __restrict__ mem_t,
        const float*  __restrict__ ent,
        const float2* __restrict__ pkbuf,
        const float*  __restrict__ qbuf,
        const float*  __restrict__ y2buf,
        float*        __restrict__ out,
        int B, int M)
{
    const int b    = blockIdx.x;
    const int wave = threadIdx.x >> 6;
    const int lane = threadIdx.x & 63;
    const int h    = wave >> 1;
    const int mhalf = M >> 1;
    const int mst  = (wave & 1) * mhalf;

    float accA = 0.0f, accS = 0.0f;
    const long ibase = ((long)h * B + b) * M + mst;

#pragma unroll 4
    for (int k = 0; k < mhalf; ++k) {
        const long t  = ibase + k;
        const int itt = __builtin_amdgcn_readfirstlane(mem_t[t]);
        const float2 pk = pkbuf[t];                         // uniform -> s_load x2
        const float  tv = ent[(long)itt * DIMV + lane];
        accS += pk.x;
        accA = fmaf(pk.x * pk.y, tv, accA);
    }

    __shared__ float A_l[4][DIMV];
    __shared__ float S_l[4];
    A_l[wave][lane] = accA;
    if (lane == 0) S_l[wave] = accS;
    __syncthreads();

    if (wave == 0) {
        const float q  = qbuf[(long)b * DIMV + lane];
        const float y2 = y2buf[b];

        float k0 = (A_l[0][lane] + A_l[1][lane]) * frcp(fmaxf(S_l[0] + S_l[1], F_EPS));
        float k1 = (A_l[2][lane] + A_l[3][lane]) * frcp(fmaxf(S_l[2] + S_l[3], F_EPS));
        float n0 = k0 * k0, n1 = k1 * k1;
        wave_sum2(n0, n1);
        float p20 = frsq(fmaxf(1.0f - n0, F_EPS));
        float p21 = frsq(fmaxf(1.0f - n1, F_EPS));
        float o   = (p20 * k0 + p21 * k1) * frcp(fmaxf(p20 + p21, F_EPS));

        float oo = o * o, oq = o * q;
        wave_sum2(oo, oq);
        float kd    = 1.0f + sqrtf(fmaxf(1.0f - oo, F_EPS));
        float invkd = frcp(kd);
        float ko2   = oo * invkd * invkd;
        float nk    = fmaxf(sqrtf(ko2), F_MINN);
        float ps    = (nk > F_MAXN) ? F_MAXN * frcp(nk) : 1.0f;
        float x2    = (nk * ps) * (nk * ps);
        float xy    = -(ps * invkd) * oq;

        float A_  = 1.0f + 2.0f * xy + y2;
        float B_  = 1.0f - x2;
        float nm2 = fmaxf(A_ * A_ * x2 + B_ * B_ * y2 + 2.0f * A_ * B_ * xy, 0.0f);
        float den = fmaxf(1.0f + 2.0f * xy + x2 * y2, 1e-15f);
        float v   = fminf(sqrtf(nm2) * frcp(den), 1.0f - F_EPS);
        float dd  = __logf((1.0f + v) * frcp(1.0f - v));
        float d2  = dd * dd;

        float scr = frcp(__expf(fminf(d2 - 2.0f, 40.0f)) + 1.0f);
        if (lane == 0) out[b] = scr;
    }
}

extern "C" void kernel_launch(void* const* d_in, const int* in_sizes, int n_in,
                              void* d_out, int out_size, void* d_ws, size_t ws_size,
                              hipStream_t stream) {
    // 0 users 1 items 2 labels 3 mem_h 4 mem_r 5 mem_t 6 entity 7 rela_plus 8 relation
    const int*   items = (const int*)d_in[1];
    const int*   mh    = (const int*)d_in[3];
    const int*   mr    = (const int*)d_in[4];
    const int*   mt    = (const int*)d_in[5];
    const float* ent   = (const float*)d_in[6];
    const float* rel   = (const float*)d_in[8];
    float* out = (float*)d_out;

    const int B = in_sizes[1];              // 1024
    const int n = in_sizes[3];              // H*B*M = 65536
    const int M = n / (2 * B);              // 32 (H=2)

    // ws layout (floats): qbuf[B*64] | y2[B] | pk[2*n] | hist[32] cursor[32] bins[n] (ints)
    float*  qbuf   = (float*)d_ws;
    float*  y2buf  = qbuf + (size_t)B * DIMV;
    float2* pkbuf  = (float2*)(y2buf + B);
    int*    hist   = (int*)((float*)pkbuf + 2 * (size_t)n);
    int*    cursor = hist + 32;
    int*    bins   = cursor + 32;

    hipMemsetAsync(hist, 0, 32 * sizeof(int), stream);
    k_hist<<<dim3(64), dim3(256), 0, stream>>>(mr, n, hist);
    k_scan<<<dim3(1), dim3(64), 0, stream>>>(hist, cursor);
    {
        int g = (n + 1023) / 1024;          // 4 items per thread @256 thr
        k_scatter<<<dim3(g), dim3(256), 0, stream>>>(mr, n, cursor, bins);
    }
    k_q<<<dim3((B + 3) / 4), dim3(256), 0, stream>>>(items, ent, qbuf, y2buf, B);

    const int per_wave = 16;
    const int g_main = (n + per_wave * 4 - 1) / (per_wave * 4);
    if (M == 32 && B == 1024)
        k_main<32, 1024><<<dim3(g_main), dim3(256), 0, stream>>>(
            mh, mr, mt, ent, rel, bins, qbuf, y2buf, pkbuf, M, B, n, per_wave);
    else
        k_main<0, 0><<<dim3(g_main), dim3(256), 0, stream>>>(
            mh, mr, mt, ent, rel, bins, qbuf, y2buf, pkbuf, M, B, n, per_wave);

    k_agg<<<dim3(B), dim3(256), 0, stream>>>(mt, ent, pkbuf, qbuf, y2buf, out, B, M);
}